// Round 7
// baseline (157.156 us; speedup 1.0000x reference)
//
#include <hip/hip_runtime.h>

#define N_NODES 50000
#define N_EDGES 800000
#define F 64
#define CHUNK 3072       // edges per partition workgroup (262 blocks > 256 CUs)
#define NWG1 ((N_EDGES + CHUNK - 1) / CHUNK)   // 261
#define NBUCK 196        // coarse buckets: dst >> 8
#define BSTRIDE 8192     // fixed per-bucket capacity (mean 4082, sigma ~64)
#define NWTILE (N_NODES / 16)   // 3125 exact
#define NSENT N_NODES    // sentinel zero-row id used for segment padding (R21)

typedef __attribute__((ext_vector_type(8))) _Float16 half8;   // 16 B
typedef __attribute__((ext_vector_type(4))) float f32x4;
typedef __attribute__((ext_vector_type(8))) unsigned short ushort8v; // 16 B

// ---------- K1: partition into fixed-capacity buckets + f16 convert + W prep ----
__global__ __launch_bounds__(256) void partition_conv(
    const int*    __restrict__ src, const int* __restrict__ dst,
    const float4* __restrict__ xin,      // [N*16] float4 view of x
    half8*        __restrict__ x16,      // [(N+16)*8] f16 rows (+ sentinel row)
    unsigned short* __restrict__ h116,   // [(N+16)*64] (sentinel row zeroed here)
    const float*  __restrict__ W1, const float* __restrict__ W2,
    _Float16*     __restrict__ Wt1, _Float16* __restrict__ Wt2,
    unsigned*     __restrict__ bcur,     // [256] zeroed cursors
    unsigned*     __restrict__ ebuf) {   // [NBUCK*BSTRIDE] strided buckets
  int t = threadIdx.x, b = blockIdx.x;
  if (b == NWG1) {                       // W prep block
    for (int i = t; i < 64 * 128; i += 256) {
      int n = i >> 7, k = i & 127;       // Wt[n][k] = W[k][n]
      Wt1[i] = (_Float16)W1[k * 64 + n];
      Wt2[i] = (_Float16)W2[k * 64 + n];
    }
    // zero sentinel rows (gathered by pad ids; contribute exact +0.0)
    if (t < 32) ((unsigned*)(x16 + (size_t)NSENT * 8))[t] = 0;            // 128 B
    if (t >= 64 && t < 96) ((unsigned*)h116)[(size_t)NSENT * 32 + (t - 64)] = 0;
    return;
  }
  __shared__ int hist[256], lscan[256], lcur[256], gbase[256];
  __shared__ unsigned stage[CHUNK];      // 12 KB
  hist[t] = 0; __syncthreads();
  int e0 = b * CHUNK;
  int cnt = N_EDGES - e0; if (cnt > CHUNK) cnt = CHUNK;
  for (int i = t; i < cnt; i += 256) atomicAdd(&hist[dst[e0 + i] >> 8], 1);

  // f32 -> f16 feature conversion, grid-stride
  const int TOT = N_NODES * F / 8;
  for (int i = b * 256 + t; i < TOT; i += NWG1 * 256) {
    float4 a = xin[i * 2], c = xin[i * 2 + 1];
    half8 hh;
    hh[0] = (_Float16)a.x; hh[1] = (_Float16)a.y;
    hh[2] = (_Float16)a.z; hh[3] = (_Float16)a.w;
    hh[4] = (_Float16)c.x; hh[5] = (_Float16)c.y;
    hh[6] = (_Float16)c.z; hh[7] = (_Float16)c.w;
    x16[i] = hh;
  }
  __syncthreads();

  int v = hist[t];
  lscan[t] = v; __syncthreads();
  for (int off = 1; off < 256; off <<= 1) {
    int a = (t >= off) ? lscan[t - off] : 0;
    __syncthreads();
    lscan[t] += a;
    __syncthreads();
  }
  lscan[t] -= v;                         // exclusive local scan
  lcur[t] = lscan[t];
  if (v > 0) gbase[t] = (int)atomicAdd(&bcur[t], (unsigned)v);  // in-bucket base
  __syncthreads();

  for (int i = t; i < cnt; i += 256) {
    int d = dst[e0 + i], s = src[e0 + i];
    int bb = d >> 8;
    int p = atomicAdd(&lcur[bb], 1);
    stage[p] = ((unsigned)bb << 24) | ((unsigned)(d & 255) << 16) | (unsigned)s;
  }
  __syncthreads();
  for (int i = t; i < cnt; i += 256) {
    unsigned e = stage[i];
    int bb = e >> 24;
    ebuf[bb * BSTRIDE + gbase[bb] + (i - lscan[bb])] = e;   // coalesced runs
  }
}

// ---------- K2: per-bucket counting sort, split by key half-range ----------
// (R21) Per-node segments PADDED to multiples of 16 with SENTINEL id NSENT
// (zero feature row -> unconditional adds are exact). row_start 32B-aligned.
__global__ __launch_bounds__(256) void bucket_sort(
    const unsigned* __restrict__ ebuf, const unsigned* __restrict__ bcur,
    unsigned short* __restrict__ edge_src, int* __restrict__ row_start,
    int* __restrict__ deg) {
  __shared__ int lhist[128], lscan[128], lcur[128];
  __shared__ unsigned short srt[BSTRIDE / 2];    // 8 KB
  int B = blockIdx.x, t = threadIdx.x;
  int b = B >> 1, h = B & 1;
  int s0 = b * BSTRIDE;
  int cnt = (int)bcur[b];

  if (t < 128) lhist[t] = 0;
  __syncthreads();
  for (int i = t; i < cnt; i += 256) {
    int bin = (int)((ebuf[s0 + i] >> 16) & 255);
    if ((bin >> 7) == h) atomicAdd(&lhist[bin & 127], 1);
  }
  __syncthreads();

  int v  = (t < 128) ? lhist[t] : 0;
  int pv = (v + 15) & ~15;               // padded segment size (16-aligned)
  if (t < 128) lscan[t] = pv;
  __syncthreads();
  for (int off = 1; off < 128; off <<= 1) {
    int a = (t >= off && t < 128) ? lscan[t - off] : 0;
    __syncthreads();
    if (t < 128) lscan[t] += a;
    __syncthreads();
  }
  if (t < 128) { lscan[t] -= pv; lcur[t] = lscan[t]; }   // exclusive padded scan
  __syncthreads();

  int total_p = lscan[127] + ((lhist[127] + 15) & ~15); // padded half size
  int base    = h * (BSTRIDE / 2);                      // fixed half offset

  for (int i = t; i < cnt; i += 256) {
    unsigned e = ebuf[s0 + i];
    int bin = (int)((e >> 16) & 255);
    if ((bin >> 7) == h) {
      int p = atomicAdd(&lcur[bin & 127], 1);
      srt[p] = (unsigned short)(e & 0xFFFFu);
    }
  }
  __syncthreads();
  if (t < 128) {                          // sentinel-fill pad slots (zero row)
    int p0 = lscan[t];
    for (int j = v; j < pv; ++j) srt[p0 + j] = (unsigned short)NSENT;
  }
  __syncthreads();

  for (int i = t; i < total_p; i += 256) edge_src[s0 + base + i] = srt[i];  // 2B coalesced

  if (t < 128) {
    int n = b * 256 + h * 128 + t;
    if (n < N_NODES) { row_start[n] = s0 + base + lscan[t]; deg[n] = v; }
  }
}

// ---------- K3: aggregate-only kernel (R22 split) ----------
// No LDS, no barrier, no MFMA phase: pure gather TLP. Octet o of each wave
// owns one node; lane q holds feature octet q. Sentinel-padded segments ->
// all 8-wide batches full & unconditional. Lean body (~60 VGPR) +
// launch_bounds(256,8) -> up to 8 waves/SIMD of latency hiding (R5 measured
// only 32% occupancy on the fused kernel; barrier-straggler coupling gone).
// Accumulation order over real edges unchanged; pad adds are exact +0.0.
__global__ __launch_bounds__(256, 8) void sage_aggregate(
    const half8*    __restrict__ feat16,    // [N+16,8] gather source
    const int*      __restrict__ row_start,
    const int*      __restrict__ deg,
    const unsigned short* __restrict__ edge_src,
    half8*          __restrict__ mean16) {  // [N,8] f16 means out
  int t = threadIdx.x;
  int w = t >> 6, lane = t & 63;
  int o = lane >> 3, q = lane & 7;
  int n = blockIdx.x * 32 + w * 8 + o;
  if (n >= N_NODES) return;
  int start = row_start[n];                // multiple of 16 (32B-aligned)
  int d     = deg[n];
  half8 acc8 = (half8){0, 0, 0, 0, 0, 0, 0, 0};
  if (d > 0) {
    const ushort8v* idp = (const ushort8v*)(edge_src + start);
    int nb = ((d + 15) & ~15) >> 3;        // full 8-batches (sentinel pad)
    ushort8v iv = idp[0];
    for (int b = 0; b < nb; ++b) {
      half8 h0 = feat16[(size_t)iv[0] * 8 + q];
      half8 h1 = feat16[(size_t)iv[1] * 8 + q];
      half8 h2 = feat16[(size_t)iv[2] * 8 + q];
      half8 h3 = feat16[(size_t)iv[3] * 8 + q];
      half8 h4 = feat16[(size_t)iv[4] * 8 + q];
      half8 h5 = feat16[(size_t)iv[5] * 8 + q];
      half8 h6 = feat16[(size_t)iv[6] * 8 + q];
      half8 h7 = feat16[(size_t)iv[7] * 8 + q];
      ushort8v nv;
      bool more = (b + 1 < nb);
      if (more) nv = idp[b + 1];           // id prefetch under feat latency
      acc8 += h0; acc8 += h1; acc8 += h2; acc8 += h3;
      acc8 += h4; acc8 += h5; acc8 += h6; acc8 += h7;
      if (more) iv = nv;
    }
  }
  float inv = (d > 0) ? 1.0f / (float)d : 0.0f;
  half8 hm;
  #pragma unroll
  for (int k = 0; k < 8; ++k) hm[k] = (_Float16)((float)acc8[k] * inv);
  mean16[(size_t)n * 8 + q] = hm;          // coalesced: 128 B per octet
}

// ---------- K4: linear-only kernel (R22 split) ----------
// One wave per 16-node tile; all 4 column-tiles (16 MFMAs/wave). Reads self
// rows + mean16 rows, same MFMA order as fused version -> bitwise identical.
__global__ __launch_bounds__(256) void sage_linear(
    const _Float16* __restrict__ self16,    // [N,64]
    const half8*    __restrict__ mean16,    // [N,8]
    const _Float16* __restrict__ Wt,        // [64,128]  Wt[n][k] = W[k][n]
    const float*    __restrict__ bias,      // [64]
    float*          __restrict__ outf,      // [N,64] f32 or null
    unsigned short* __restrict__ out16,     // [N,64] f16 or null
    int do_relu) {
  int t = threadIdx.x;
  int w = t >> 6, lane = t & 63;
  int wt = blockIdx.x * 4 + w;
  if (wt >= NWTILE) return;
  int m = lane & 15, quad = lane >> 4;
  size_t arow = (size_t)(wt * 16 + m) * 64 + quad * 8;
  half8 a0 = *(const half8*)(self16 + arow);
  half8 a1 = *(const half8*)(self16 + arow + 32);
  size_t mrow = (size_t)(wt * 16 + m) * 8;
  half8 a2 = mean16[mrow + quad];           // halves quad*8..quad*8+7
  half8 a3 = mean16[mrow + quad + 4];       // halves 32+quad*8..

  #pragma unroll
  for (int nt = 0; nt < 4; ++nt) {
    float bv = bias[nt * 16 + m];           // col = lane&15
    f32x4 acc = (f32x4){bv, bv, bv, bv};
    const _Float16* wrow = Wt + (size_t)(nt * 16 + m) * 128 + quad * 8;
    half8 b0 = *(const half8*)(wrow);
    half8 b1 = *(const half8*)(wrow + 32);
    half8 b2 = *(const half8*)(wrow + 64);
    half8 b3 = *(const half8*)(wrow + 96);
    acc = __builtin_amdgcn_mfma_f32_16x16x32_f16(a0, b0, acc, 0, 0, 0);
    acc = __builtin_amdgcn_mfma_f32_16x16x32_f16(a1, b1, acc, 0, 0, 0);
    acc = __builtin_amdgcn_mfma_f32_16x16x32_f16(a2, b2, acc, 0, 0, 0);
    acc = __builtin_amdgcn_mfma_f32_16x16x32_f16(a3, b3, acc, 0, 0, 0);
    #pragma unroll
    for (int r = 0; r < 4; ++r) {
      size_t off = (size_t)(wt * 16 + quad * 4 + r) * 64 + nt * 16 + m;
      float v = acc[r];
      if (do_relu) v = fmaxf(v, 0.0f);
      if (outf)  outf[off] = v;
      if (out16) { _Float16 hv = (_Float16)v; out16[off] = *(unsigned short*)&hv; }
    }
  }
}

extern "C" void kernel_launch(void* const* d_in, const int* in_sizes, int n_in,
                              void* d_out, int out_size, void* d_ws, size_t ws_size,
                              hipStream_t stream) {
  const float* x  = (const float*)d_in[0];
  const int*   ei = (const int*)d_in[1];   // [2,E]: row 0 = src, row 1 = dst
  const float* W1 = (const float*)d_in[2];
  const float* b1 = (const float*)d_in[3];
  const float* W2 = (const float*)d_in[4];
  const float* b2 = (const float*)d_in[5];
  float* out = (float*)d_out;

  const int* src = ei;
  const int* dst = ei + N_EDGES;

  // ws layout (int offsets), all 16B-aligned:
  //   bcur@0[256] | deg@256[50048] | row_start@50304[50048] |
  //   edge_src@100352[802816] | ebuf@903168[1605632] |
  //   x16@2508800[1600512 (+sentinel)] | h116@4109312[1600512] |
  //   Wt1@5709824[4096] | Wt2@5713920[4096] | mean16@5718016[1600000]
  //   total 7,318,016 ints = 29.3 MB (ws is ~268 MB per harness poison fill)
  int* wsi       = (int*)d_ws;
  unsigned* bcur = (unsigned*)wsi;
  int* deg       = wsi + 256;
  int* row_start = wsi + 50304;
  unsigned short* edge_src = (unsigned short*)(wsi + 100352);
  unsigned* ebuf = (unsigned*)(wsi + 903168);
  half8* x16     = (half8*)(wsi + 2508800);
  unsigned short* h116 = (unsigned short*)(wsi + 4109312);
  _Float16* Wt1  = (_Float16*)(wsi + 5709824);
  _Float16* Wt2  = (_Float16*)(wsi + 5713920);
  half8* mean16  = (half8*)(wsi + 5718016);

  hipMemsetAsync(bcur, 0, 256 * sizeof(unsigned), stream);

  dim3 blk(256);
  partition_conv<<<NWG1 + 1, blk, 0, stream>>>(
      src, dst, (const float4*)x, x16, h116, W1, W2, Wt1, Wt2, bcur, ebuf);
  bucket_sort<<<NBUCK * 2, blk, 0, stream>>>(ebuf, bcur, edge_src, row_start, deg);

  dim3 grd_agg((N_NODES + 31) / 32);     // 1563 blocks, 8 nodes/wave
  dim3 grd_lin((NWTILE + 3) / 4);        // 782 blocks, 1 tile/wave

  // Layer 1: mean1 = agg(x16); h1 = relu([x||mean1]W1+b1) kept as f16
  sage_aggregate<<<grd_agg, blk, 0, stream>>>(x16, row_start, deg, edge_src, mean16);
  sage_linear<<<grd_lin, blk, 0, stream>>>((const _Float16*)x16, mean16,
                                           Wt1, b1, nullptr, h116, 1);
  // Layer 2: mean2 = agg(h1); out = [h1||mean2]W2+b2 (f32)
  sage_aggregate<<<grd_agg, blk, 0, stream>>>((const half8*)h116, row_start, deg,
                                              edge_src, mean16);
  sage_linear<<<grd_lin, blk, 0, stream>>>((const _Float16*)h116, mean16,
                                           Wt2, b2, out, nullptr, 0);
}

// Round 8
// 143.832 us; speedup vs baseline: 1.0926x; 1.0926x over previous
//
#include <hip/hip_runtime.h>

#define N_NODES 50000
#define N_EDGES 800000
#define F 64
#define CHUNK 3072       // edges per partition workgroup (262 blocks > 256 CUs)
#define NWG1 ((N_EDGES + CHUNK - 1) / CHUNK)   // 261
#define NBUCK 196        // coarse buckets: dst >> 8
#define BSTRIDE 8192     // fixed per-bucket capacity (mean 4082, sigma ~64)
#define NWTILE (N_NODES / 16)   // 3125 exact
#define NSENT N_NODES    // sentinel zero-row id used for segment padding (R21)

typedef __attribute__((ext_vector_type(8))) _Float16 half8;   // 16 B
typedef __attribute__((ext_vector_type(4))) float f32x4;
typedef __attribute__((ext_vector_type(8))) unsigned short ushort8v; // 16 B

// ---------- K1: partition into fixed-capacity buckets + f16 convert + W prep ----
__global__ __launch_bounds__(256) void partition_conv(
    const int*    __restrict__ src, const int* __restrict__ dst,
    const float4* __restrict__ xin,      // [N*16] float4 view of x
    half8*        __restrict__ x16,      // [(N+16)*8] f16 rows (+ sentinel row)
    unsigned short* __restrict__ h116,   // [(N+16)*64] (sentinel row zeroed here)
    const float*  __restrict__ W1, const float* __restrict__ W2,
    _Float16*     __restrict__ Wt1, _Float16* __restrict__ Wt2,
    unsigned*     __restrict__ bcur,     // [256] zeroed cursors
    unsigned*     __restrict__ ebuf) {   // [NBUCK*BSTRIDE] strided buckets
  int t = threadIdx.x, b = blockIdx.x;
  if (b == NWG1) {                       // W prep block
    for (int i = t; i < 64 * 128; i += 256) {
      int n = i >> 7, k = i & 127;       // Wt[n][k] = W[k][n]
      Wt1[i] = (_Float16)W1[k * 64 + n];
      Wt2[i] = (_Float16)W2[k * 64 + n];
    }
    // zero sentinel rows (gathered by pad ids; contribute exact +0.0)
    if (t < 32) ((unsigned*)(x16 + (size_t)NSENT * 8))[t] = 0;            // 128 B
    if (t >= 64 && t < 96) ((unsigned*)h116)[(size_t)NSENT * 32 + (t - 64)] = 0;
    return;
  }
  __shared__ int hist[256], lscan[256], lcur[256], gbase[256];
  __shared__ unsigned stage[CHUNK];      // 12 KB
  hist[t] = 0; __syncthreads();
  int e0 = b * CHUNK;
  int cnt = N_EDGES - e0; if (cnt > CHUNK) cnt = CHUNK;
  for (int i = t; i < cnt; i += 256) atomicAdd(&hist[dst[e0 + i] >> 8], 1);

  // f32 -> f16 feature conversion, grid-stride
  const int TOT = N_NODES * F / 8;
  for (int i = b * 256 + t; i < TOT; i += NWG1 * 256) {
    float4 a = xin[i * 2], c = xin[i * 2 + 1];
    half8 hh;
    hh[0] = (_Float16)a.x; hh[1] = (_Float16)a.y;
    hh[2] = (_Float16)a.z; hh[3] = (_Float16)a.w;
    hh[4] = (_Float16)c.x; hh[5] = (_Float16)c.y;
    hh[6] = (_Float16)c.z; hh[7] = (_Float16)c.w;
    x16[i] = hh;
  }
  __syncthreads();

  int v = hist[t];
  lscan[t] = v; __syncthreads();
  for (int off = 1; off < 256; off <<= 1) {
    int a = (t >= off) ? lscan[t - off] : 0;
    __syncthreads();
    lscan[t] += a;
    __syncthreads();
  }
  lscan[t] -= v;                         // exclusive local scan
  lcur[t] = lscan[t];
  if (v > 0) gbase[t] = (int)atomicAdd(&bcur[t], (unsigned)v);  // in-bucket base
  __syncthreads();

  for (int i = t; i < cnt; i += 256) {
    int d = dst[e0 + i], s = src[e0 + i];
    int bb = d >> 8;
    int p = atomicAdd(&lcur[bb], 1);
    stage[p] = ((unsigned)bb << 24) | ((unsigned)(d & 255) << 16) | (unsigned)s;
  }
  __syncthreads();
  for (int i = t; i < cnt; i += 256) {
    unsigned e = stage[i];
    int bb = e >> 24;
    ebuf[bb * BSTRIDE + gbase[bb] + (i - lscan[bb])] = e;   // coalesced runs
  }
}

// ---------- K2: per-bucket counting sort, split by key half-range ----------
// (R23) Per-node segments PADDED to multiples of 8 with SENTINEL id NSENT
// (zero feature row -> unconditional adds are exact). row_start 16B-aligned.
// NEW: per-32-node-group degree-rank permutation (perm) so the layer kernel
// can assign similar-degree nodes to the same wave (kills the wave-max
// divergence penalty, ~35% of gather instructions). lhist[] still holds each
// node's degree at this point -> rank = O(32) compares per node, free.
__global__ __launch_bounds__(256) void bucket_sort(
    const unsigned* __restrict__ ebuf, const unsigned* __restrict__ bcur,
    unsigned short* __restrict__ edge_src, int* __restrict__ row_start,
    int* __restrict__ deg, unsigned char* __restrict__ perm) {
  __shared__ int lhist[128], lscan[128], lcur[128];
  __shared__ unsigned short srt[BSTRIDE / 2];    // 8 KB
  int B = blockIdx.x, t = threadIdx.x;
  int b = B >> 1, h = B & 1;
  int s0 = b * BSTRIDE;
  int cnt = (int)bcur[b];

  if (t < 128) lhist[t] = 0;
  __syncthreads();
  for (int i = t; i < cnt; i += 256) {
    int bin = (int)((ebuf[s0 + i] >> 16) & 255);
    if ((bin >> 7) == h) atomicAdd(&lhist[bin & 127], 1);
  }
  __syncthreads();

  int v  = (t < 128) ? lhist[t] : 0;
  int pv = (v + 7) & ~7;                 // padded segment size (8-aligned)
  if (t < 128) lscan[t] = pv;
  __syncthreads();
  for (int off = 1; off < 128; off <<= 1) {
    int a = (t >= off && t < 128) ? lscan[t - off] : 0;
    __syncthreads();
    if (t < 128) lscan[t] += a;
    __syncthreads();
  }
  if (t < 128) { lscan[t] -= pv; lcur[t] = lscan[t]; }   // exclusive padded scan
  __syncthreads();

  int total_p = lscan[127] + ((lhist[127] + 7) & ~7);   // padded half size
  int base    = h * (BSTRIDE / 2);                      // fixed half offset

  for (int i = t; i < cnt; i += 256) {
    unsigned e = ebuf[s0 + i];
    int bin = (int)((e >> 16) & 255);
    if ((bin >> 7) == h) {
      int p = atomicAdd(&lcur[bin & 127], 1);
      srt[p] = (unsigned short)(e & 0xFFFFu);
    }
  }
  __syncthreads();
  if (t < 128) {                          // sentinel-fill pad slots (zero row)
    int p0 = lscan[t];
    for (int j = v; j < pv; ++j) srt[p0 + j] = (unsigned short)NSENT;
  }
  __syncthreads();

  for (int i = t; i < total_p; i += 256) edge_src[s0 + base + i] = srt[i];  // 2B coalesced

  if (t < 128) {
    int n = b * 256 + h * 128 + t;
    if (n < N_NODES) { row_start[n] = s0 + base + lscan[t]; deg[n] = v; }
    // degree-rank permutation within this node's 32-group (stable by index)
    int g0 = t & ~31;
    int rank = 0;
    #pragma unroll 8
    for (int j = 0; j < 32; ++j) {
      int dj = lhist[g0 + j];
      rank += (dj < v) || (dj == v && j < (t & 31));
    }
    perm[b * 256 + h * 128 + g0 + rank] = (unsigned char)(t & 31);
  }
}

// ---------- fused layer: octet-per-node aggregate -> LDS -> MFMA linear ----------
// Block = 4 waves = 32 nodes = 2 MFMA tiles.
// Phase 1 (R23): octet (w,o) handles node perm[w*8+o] of the block's 32-group
//   -> each wave gets 8 SIMILAR-degree nodes (wave trip = max over octets ~=
//   mean, was ~1.35x mean). 8-granular sentinel padding (was 16) cuts padded
//   slots 24 -> 18.9 per node. Simple 8-wide unconditional batches with id
//   prefetch. Per-node accumulation order over real edges unchanged; pad adds
//   are exact +0.0 -> bitwise-identical output.
// Phase 2: unchanged; lmean slot = original local index, tiles intact.
__global__ __launch_bounds__(256) void sage_layer_fused(
    const half8*    __restrict__ feat16,    // [N+16,8] gather source (= self16)
    const _Float16* __restrict__ self16,    // [N,64]
    const int*      __restrict__ row_start,
    const int*      __restrict__ deg,
    const unsigned short* __restrict__ edge_src,
    const unsigned char* __restrict__ perm, // [~N] degree-rank perm (32-groups)
    const _Float16* __restrict__ Wt,        // [64,128]  Wt[n][k] = W[k][n]
    const float*    __restrict__ bias,      // [64]
    float*          __restrict__ outf,      // [N,64] f32 or null
    unsigned short* __restrict__ out16,     // [N,64] f16 or null
    int do_relu) {
  __shared__ _Float16 lmean[32 * 72];       // node stride 72 halves, 4.6 KB
  int t = threadIdx.x;
  int w = t >> 6, lane = t & 63;

  // ---- phase 1: aggregate 8 nodes per wave (degree-ranked octets) ----
  {
    int o = lane >> 3, q = lane & 7;
    int ln = (int)perm[blockIdx.x * 32 + w * 8 + o];   // local node 0..31
    int n = blockIdx.x * 32 + ln;
    if (n < N_NODES) {
      int start = row_start[n];            // multiple of 8 (16B-aligned)
      int d     = deg[n];
      half8 acc8 = (half8){0, 0, 0, 0, 0, 0, 0, 0};
      if (d > 0) {
        const ushort8v* idp = (const ushort8v*)(edge_src + start);
        int nb = (d + 7) >> 3;             // full 8-batches (sentinel pad)
        ushort8v iv = idp[0];
        for (int b = 0; b < nb; ++b) {
          half8 h0 = feat16[(size_t)iv[0] * 8 + q];
          half8 h1 = feat16[(size_t)iv[1] * 8 + q];
          half8 h2 = feat16[(size_t)iv[2] * 8 + q];
          half8 h3 = feat16[(size_t)iv[3] * 8 + q];
          half8 h4 = feat16[(size_t)iv[4] * 8 + q];
          half8 h5 = feat16[(size_t)iv[5] * 8 + q];
          half8 h6 = feat16[(size_t)iv[6] * 8 + q];
          half8 h7 = feat16[(size_t)iv[7] * 8 + q];
          ushort8v nv;
          bool more = (b + 1 < nb);
          if (more) nv = idp[b + 1];       // id prefetch under feat latency
          acc8 += h0; acc8 += h1; acc8 += h2; acc8 += h3;
          acc8 += h4; acc8 += h5; acc8 += h6; acc8 += h7;
          if (more) iv = nv;
        }
      }
      float inv = (d > 0) ? 1.0f / (float)d : 0.0f;
      half8 hm;
      #pragma unroll
      for (int k = 0; k < 8; ++k) hm[k] = (_Float16)((float)acc8[k] * inv);
      *(half8*)&lmean[ln * 72 + q * 8] = hm;
    }
  }
  __syncthreads();

  // ---- phase 2: MFMA linear; wave w does nt-half (w&1) of tile (w>>1) ----
  int tile = w >> 1;
  int wt = blockIdx.x * 2 + tile;
  if (wt >= NWTILE) return;
  int m = lane & 15, quad = lane >> 4;
  size_t arow = (size_t)(wt * 16 + m) * 64 + quad * 8;
  half8 a0 = *(const half8*)(self16 + arow);
  half8 a1 = *(const half8*)(self16 + arow + 32);
  int ln = tile * 16 + m;                   // local node 0..31
  half8 a2 = *(const half8*)&lmean[ln * 72 + quad * 8];
  half8 a3 = *(const half8*)&lmean[ln * 72 + quad * 8 + 32];

  int nt0 = (w & 1) * 2;                    // 0 or 2
  #pragma unroll
  for (int i = 0; i < 2; ++i) {
    int nt = nt0 + i;
    float bv = bias[nt * 16 + m];           // col = lane&15
    f32x4 acc = (f32x4){bv, bv, bv, bv};
    const _Float16* wrow = Wt + (size_t)(nt * 16 + m) * 128 + quad * 8;
    half8 b0 = *(const half8*)(wrow);
    half8 b1 = *(const half8*)(wrow + 32);
    half8 b2 = *(const half8*)(wrow + 64);
    half8 b3 = *(const half8*)(wrow + 96);
    acc = __builtin_amdgcn_mfma_f32_16x16x32_f16(a0, b0, acc, 0, 0, 0);
    acc = __builtin_amdgcn_mfma_f32_16x16x32_f16(a1, b1, acc, 0, 0, 0);
    acc = __builtin_amdgcn_mfma_f32_16x16x32_f16(a2, b2, acc, 0, 0, 0);
    acc = __builtin_amdgcn_mfma_f32_16x16x32_f16(a3, b3, acc, 0, 0, 0);
    #pragma unroll
    for (int r = 0; r < 4; ++r) {
      size_t off = (size_t)(wt * 16 + quad * 4 + r) * 64 + nt * 16 + m;
      float v = acc[r];
      if (do_relu) v = fmaxf(v, 0.0f);
      if (outf)  outf[off] = v;
      if (out16) { _Float16 hv = (_Float16)v; out16[off] = *(unsigned short*)&hv; }
    }
  }
}

extern "C" void kernel_launch(void* const* d_in, const int* in_sizes, int n_in,
                              void* d_out, int out_size, void* d_ws, size_t ws_size,
                              hipStream_t stream) {
  const float* x  = (const float*)d_in[0];
  const int*   ei = (const int*)d_in[1];   // [2,E]: row 0 = src, row 1 = dst
  const float* W1 = (const float*)d_in[2];
  const float* b1 = (const float*)d_in[3];
  const float* W2 = (const float*)d_in[4];
  const float* b2 = (const float*)d_in[5];
  float* out = (float*)d_out;

  const int* src = ei;
  const int* dst = ei + N_EDGES;

  // ws layout (int offsets), all 16B-aligned:
  //   bcur@0[256] | deg@256[50048] | row_start@50304[50048] |
  //   edge_src@100352[802816] | ebuf@903168[1605632] |
  //   x16@2508800[1600512 (+sentinel)] | h116@4109312[1600512] |
  //   Wt1@5709824[4096] | Wt2@5713920[4096] | perm@5718016[12544 bytes-as-ints]
  //   total 5,730,560 ints = 22.9 MB
  int* wsi       = (int*)d_ws;
  unsigned* bcur = (unsigned*)wsi;
  int* deg       = wsi + 256;
  int* row_start = wsi + 50304;
  unsigned short* edge_src = (unsigned short*)(wsi + 100352);
  unsigned* ebuf = (unsigned*)(wsi + 903168);
  half8* x16     = (half8*)(wsi + 2508800);
  unsigned short* h116 = (unsigned short*)(wsi + 4109312);
  _Float16* Wt1  = (_Float16*)(wsi + 5709824);
  _Float16* Wt2  = (_Float16*)(wsi + 5713920);
  unsigned char* perm = (unsigned char*)(wsi + 5718016);

  hipMemsetAsync(bcur, 0, 256 * sizeof(unsigned), stream);

  dim3 blk(256);
  partition_conv<<<NWG1 + 1, blk, 0, stream>>>(
      src, dst, (const float4*)x, x16, h116, W1, W2, Wt1, Wt2, bcur, ebuf);
  bucket_sort<<<NBUCK * 2, blk, 0, stream>>>(ebuf, bcur, edge_src, row_start,
                                             deg, perm);

  dim3 grd_fused((N_NODES + 31) / 32);   // 1563 blocks = 3126 tiles >= 3125

  // Layer 1: h1 = relu([x||mean]W1+b1), kept only as f16
  sage_layer_fused<<<grd_fused, blk, 0, stream>>>(
      x16, (const _Float16*)x16, row_start, deg, edge_src, perm,
      Wt1, b1, nullptr, h116, 1);
  // Layer 2: out = [h1||mean]W2+b2 (f32)
  sage_layer_fused<<<grd_fused, blk, 0, stream>>>(
      (const half8*)h116, (const _Float16*)h116, row_start, deg, edge_src, perm,
      Wt2, b2, out, nullptr, 0);
}